// Round 4
// baseline (81.261 us; speedup 1.0000x reference)
//
#include <hip/hip_runtime.h>
#include <math.h>

// Problem constants (fixed by the reference)
constexpr int B = 8192;
constexpr int D = 128;
constexpr int K = 256;
constexpr int CHUNKS = 16;        // K split across blocks
constexpr int KC = K / CHUNKS;    // 16 centroids per chunk-block
constexpr int RPB = 128;          // rows per block (2 threads per row)
constexpr int RB = B / RPB;       // 64 row-blocks
constexpr int CB = B / 256;       // combine blocks = 32

// ws layout (floats)
//   cc        : [0, 256)
//   part_reg  : [256, 512)
//   part_loss : [512, 512+CB)
//   disty     : [1024, 1024+B)
//   s_part    : [1024+B, 1024+B+CHUNKS*B)

// --- Kernel 1: reg term + cc byproduct -------------------------------------
__global__ __launch_bounds__(256) void reg_kernel(const float* __restrict__ centers,
                                                  float* __restrict__ part_reg,
                                                  float* __restrict__ cc) {
  const int i = blockIdx.x;
  const int j = threadIdx.x;
  const float* ci = centers + (size_t)i * D;  // uniform -> scalar loads
  const float* cj = centers + (size_t)j * D;  // per-lane
  float pd = 0.f, ccj = 0.f;
#pragma unroll
  for (int q = 0; q < D / 4; ++q) {
    float4 a  = reinterpret_cast<const float4*>(ci)[q];
    float4 bq = reinterpret_cast<const float4*>(cj)[q];
    float dx = a.x - bq.x, dy = a.y - bq.y, dz = a.z - bq.z, dw = a.w - bq.w;
    pd = fmaf(dx, dx, fmaf(dy, dy, fmaf(dz, dz, fmaf(dw, dw, pd))));
    ccj = fmaf(bq.x, bq.x, fmaf(bq.y, bq.y, fmaf(bq.z, bq.z, fmaf(bq.w, bq.w, ccj))));
  }
  if (i == 0) cc[j] = ccj;
  if (j == i) pd = INFINITY;
  const int lane = threadIdx.x & 63;
  const int wid  = threadIdx.x >> 6;
#pragma unroll
  for (int off = 32; off; off >>= 1) pd = fminf(pd, __shfl_xor(pd, off));
  __shared__ float red[4];
  if (lane == 0) red[wid] = pd;
  __syncthreads();
  if (threadIdx.x == 0) {
    float m = fminf(fminf(red[0], red[1]), fminf(red[2], red[3]));
    part_reg[i] = -logf(m);
  }
}

// --- Kernel 2: main — 2 threads per row, half-D each, k-chunked ------------
// Thread pair (2r, 2r+1) owns batch row b; each holds 64 h-values in VGPRs.
// Per centroid: 64 FMAs into 4 independent accumulators, one shfl_xor to
// combine halves. No barriers/LDS in the hot loop. Grid 1024 -> 4 blocks/CU.
__global__ __launch_bounds__(256, 4) void main_kernel(
    const float* __restrict__ h, const int* __restrict__ y,
    const float* __restrict__ centers, const float* __restrict__ cc,
    float* __restrict__ s_part, float* __restrict__ disty) {
  const int t = threadIdx.x;
  const int half = t & 1;
  const int r = t >> 1;
  const int rb = blockIdx.x & (RB - 1);
  const int chunk = blockIdx.x / RB;
  const int b = rb * RPB + r;

  // Load this thread's half of the h row into registers and pin.
  float hv[64];
  const float4* hrow = reinterpret_cast<const float4*>(h + (size_t)b * D) + half * 16;
#pragma unroll
  for (int q = 0; q < 16; ++q) {
    float4 v = hrow[q];
    hv[4 * q + 0] = v.x;
    hv[4 * q + 1] = v.y;
    hv[4 * q + 2] = v.z;
    hv[4 * q + 3] = v.w;
  }
#pragma unroll
  for (int d = 0; d < 64; ++d) asm volatile("" : "+v"(hv[d]));

  float hhh = 0.f;
#pragma unroll
  for (int d = 0; d < 64; ++d) hhh = fmaf(hv[d], hv[d], hhh);
  const float hh = hhh + __shfl_xor(hhh, 1);

  const int yb = y[b];
  float s = 0.f, dy = 0.f;
  const int k0 = chunk * KC;

#pragma unroll 2
  for (int kk = 0; kk < KC; ++kk) {
    const int k = k0 + kk;
    const float4* ck4 =
        reinterpret_cast<const float4*>(centers + (size_t)k * D) + half * 16;
    const float cck = cc[k];
    float acc[4] = {0.f, 0.f, 0.f, 0.f};
#pragma unroll
    for (int q = 0; q < 16; ++q) {
      float4 cq = ck4[q];
      acc[q & 3] = fmaf(cq.x, hv[4 * q + 0], acc[q & 3]);
      acc[q & 3] = fmaf(cq.y, hv[4 * q + 1], acc[q & 3]);
      acc[q & 3] = fmaf(cq.z, hv[4 * q + 2], acc[q & 3]);
      acc[q & 3] = fmaf(cq.w, hv[4 * q + 3], acc[q & 3]);
    }
    float dot = (acc[0] + acc[1]) + (acc[2] + acc[3]);
    dot += __shfl_xor(dot, 1);
    float dist = fmaxf(hh + cck - 2.f * dot, 0.f);
    if (k == yb) dy = dist;
    s += __expf(-sqrtf(dist));
  }

  if (half == 0) {
    s_part[(size_t)chunk * B + b] = s;
    if ((yb / KC) == chunk) disty[b] = dy;
  }
}

// --- Kernel 3: combine per-chunk partials into per-block loss sums ---------
__global__ __launch_bounds__(256) void combine_kernel(
    const float* __restrict__ s_part, const float* __restrict__ disty,
    float* __restrict__ part_loss) {
  const int t = threadIdx.x;
  const int b = blockIdx.x * 256 + t;
  float s = 0.f;
#pragma unroll
  for (int c = 0; c < CHUNKS; ++c) s += s_part[(size_t)c * B + b];
  float v = disty[b] + logf(s);
  const int lane = t & 63;
  const int wid  = t >> 6;
#pragma unroll
  for (int off = 32; off; off >>= 1) v += __shfl_xor(v, off);
  __shared__ float red[4];
  if (lane == 0) red[wid] = v;
  __syncthreads();
  if (t == 0) part_loss[blockIdx.x] = red[0] + red[1] + red[2] + red[3];
}

// --- Kernel 4: final deterministic reduction -------------------------------
__global__ __launch_bounds__(256) void final_kernel(
    const float* __restrict__ part_loss, const float* __restrict__ part_reg,
    float* __restrict__ out) {
  const int t = threadIdx.x;
  float v = part_reg[t] + (t < CB ? part_loss[t] * (1.0f / (float)B) : 0.f);
  const int lane = t & 63;
  const int wid  = t >> 6;
#pragma unroll
  for (int off = 32; off; off >>= 1) v += __shfl_xor(v, off);
  __shared__ float red[4];
  if (lane == 0) red[wid] = v;
  __syncthreads();
  if (t == 0) out[0] = red[0] + red[1] + red[2] + red[3];
}

extern "C" void kernel_launch(void* const* d_in, const int* in_sizes, int n_in,
                              void* d_out, int out_size, void* d_ws, size_t ws_size,
                              hipStream_t stream) {
  const float* h       = (const float*)d_in[0];
  const int*   y       = (const int*)d_in[1];
  const float* centers = (const float*)d_in[2];
  float* out = (float*)d_out;
  float* ws  = (float*)d_ws;

  float* cc        = ws;
  float* part_reg  = ws + 256;
  float* part_loss = ws + 512;
  float* disty     = ws + 1024;
  float* s_part    = ws + 1024 + B;

  reg_kernel<<<K, 256, 0, stream>>>(centers, part_reg, cc);
  main_kernel<<<RB * CHUNKS, 256, 0, stream>>>(h, y, centers, cc, s_part, disty);
  combine_kernel<<<CB, 256, 0, stream>>>(s_part, disty, part_loss);
  final_kernel<<<1, 256, 0, stream>>>(part_loss, part_reg, out);
}

// Round 5
// 47.637 us; speedup vs baseline: 1.7058x; 1.7058x over previous
//
#include <hip/hip_runtime.h>
#include <math.h>

// Problem constants (fixed by the reference)
constexpr int B = 8192;
constexpr int D = 128;
constexpr int K = 256;
constexpr int R = 8;              // batch rows per main block
constexpr int MB = B / R;         // 1024 main blocks
constexpr int HHB = B / 4;        // hh sub-blocks in prep

// ws layout (floats)
//   part_reg  : [0, 256)
//   hh        : [256, 256+B)
//   part_loss : [256+B, 256+B+MB)

// --- Kernel 1: fused prep — reg term (blocks 0..K) + hh (blocks K..) -------
__global__ __launch_bounds__(256) void prep_kernel(const float* __restrict__ centers,
                                                   const float* __restrict__ h,
                                                   float* __restrict__ part_reg,
                                                   float* __restrict__ hh) {
  __shared__ float red[4];
  const int lane = threadIdx.x & 63;
  const int wid  = threadIdx.x >> 6;
  if (blockIdx.x < K) {
    // part_reg[i] = -log(min_{j!=i} ||c_i - c_j||^2)
    const int i = blockIdx.x;
    const int j = threadIdx.x;
    const float* ci = centers + (size_t)i * D;  // uniform -> scalar loads
    const float* cj = centers + (size_t)j * D;  // per-lane
    float pd = 0.f;
#pragma unroll
    for (int q = 0; q < D / 4; ++q) {
      float4 a  = reinterpret_cast<const float4*>(ci)[q];
      float4 bq = reinterpret_cast<const float4*>(cj)[q];
      float dx = a.x - bq.x, dy = a.y - bq.y, dz = a.z - bq.z, dw = a.w - bq.w;
      pd = fmaf(dx, dx, fmaf(dy, dy, fmaf(dz, dz, fmaf(dw, dw, pd))));
    }
    if (j == i) pd = INFINITY;
#pragma unroll
    for (int off = 32; off; off >>= 1) pd = fminf(pd, __shfl_xor(pd, off));
    if (lane == 0) red[wid] = pd;
    __syncthreads();
    if (threadIdx.x == 0) {
      float m = fminf(fminf(red[0], red[1]), fminf(red[2], red[3]));
      part_reg[i] = -logf(m);
    }
  } else {
    // hh[b] = sum_d h[b][d]^2, 4 rows per block (one per wave)
    const int b = (blockIdx.x - K) * 4 + wid;
    const float* hb = h + (size_t)b * D;
    float v0 = hb[lane];
    float v1 = hb[lane + 64];
    float s = v0 * v0 + v1 * v1;
#pragma unroll
    for (int off = 32; off; off >>= 1) s += __shfl_xor(s, off);
    if (lane == 0) hh[b] = s;
  }
}

// --- Kernel 2: main — thread t owns centroid t, 8 batch rows per block -----
// h operands are wave-uniform (scalar s_load path, SMEM pipe); centroid row
// streams per-lane as float4 (L2-hot, 128 KB total). dot[8] = 8 independent
// accumulators, all constant-indexed -> stays in VGPRs. Block covers all 256
// centroids so logsumexp completes in-block.
__global__ __launch_bounds__(256, 4) void main_kernel(
    const float* __restrict__ h, const int* __restrict__ y,
    const float* __restrict__ centers, const float* __restrict__ hh,
    float* __restrict__ part_loss) {
  const int t = threadIdx.x;
  const int b0 = blockIdx.x * R;
  const int lane = t & 63;
  const int wid  = t >> 6;

  const float4* crow = reinterpret_cast<const float4*>(centers + (size_t)t * D);
  const float* hp = h + (size_t)b0 * D;  // uniform base

  float dot[R] = {0.f, 0.f, 0.f, 0.f, 0.f, 0.f, 0.f, 0.f};
  float ccv = 0.f;

#pragma unroll
  for (int q = 0; q < D / 4; ++q) {
    float4 c4 = crow[q];  // per-lane 16B
    ccv = fmaf(c4.x, c4.x, fmaf(c4.y, c4.y, fmaf(c4.z, c4.z, fmaf(c4.w, c4.w, ccv))));
#pragma unroll
    for (int r = 0; r < R; ++r) {
      const float4 h4 = *reinterpret_cast<const float4*>(hp + r * D + 4 * q);  // uniform -> s_load
      dot[r] = fmaf(c4.x, h4.x, dot[r]);
      dot[r] = fmaf(c4.y, h4.y, dot[r]);
      dot[r] = fmaf(c4.z, h4.z, dot[r]);
      dot[r] = fmaf(c4.w, h4.w, dot[r]);
    }
  }

  __shared__ float lds_s[4][R];
  __shared__ float lds_disty[R];
  __shared__ float lds_v[R];

  float e[R];
#pragma unroll
  for (int r = 0; r < R; ++r) {
    const float dist = fmaxf(hh[b0 + r] + ccv - 2.f * dot[r], 0.f);
    if (t == y[b0 + r]) lds_disty[r] = dist;  // exactly one thread
    e[r] = __expf(-sqrtf(dist));
  }

  // wave-reduce each of the R exp-sums, then cross-wave via LDS
#pragma unroll
  for (int r = 0; r < R; ++r) {
    float s = e[r];
#pragma unroll
    for (int off = 32; off; off >>= 1) s += __shfl_xor(s, off);
    if (lane == 0) lds_s[wid][r] = s;
  }
  __syncthreads();
  if (t < R) {
    const float tot = (lds_s[0][t] + lds_s[1][t]) + (lds_s[2][t] + lds_s[3][t]);
    lds_v[t] = lds_disty[t] + __logf(tot);
  }
  __syncthreads();
  if (t == 0) {
    float a = 0.f;
#pragma unroll
    for (int r = 0; r < R; ++r) a += lds_v[r];
    part_loss[blockIdx.x] = a;
  }
}

// --- Kernel 3: final deterministic reduction -------------------------------
__global__ __launch_bounds__(256) void final_kernel(
    const float* __restrict__ part_loss, const float* __restrict__ part_reg,
    float* __restrict__ out) {
  const int t = threadIdx.x;
  float pl = 0.f;
#pragma unroll
  for (int j = 0; j < MB / 256; ++j) pl += part_loss[t + 256 * j];
  float v = part_reg[t] + pl * (1.0f / (float)B);
  const int lane = t & 63;
  const int wid  = t >> 6;
#pragma unroll
  for (int off = 32; off; off >>= 1) v += __shfl_xor(v, off);
  __shared__ float red[4];
  if (lane == 0) red[wid] = v;
  __syncthreads();
  if (t == 0) out[0] = red[0] + red[1] + red[2] + red[3];
}

extern "C" void kernel_launch(void* const* d_in, const int* in_sizes, int n_in,
                              void* d_out, int out_size, void* d_ws, size_t ws_size,
                              hipStream_t stream) {
  const float* h       = (const float*)d_in[0];
  const int*   y       = (const int*)d_in[1];
  const float* centers = (const float*)d_in[2];
  float* out = (float*)d_out;
  float* ws  = (float*)d_ws;

  float* part_reg  = ws;
  float* hh        = ws + 256;
  float* part_loss = ws + 256 + B;

  prep_kernel<<<K + HHB, 256, 0, stream>>>(centers, h, part_reg, hh);
  main_kernel<<<MB, 256, 0, stream>>>(h, y, centers, hh, part_loss);
  final_kernel<<<1, 256, 0, stream>>>(part_loss, part_reg, out);
}

// Round 6
// 20.480 us; speedup vs baseline: 3.9678x; 2.3260x over previous
//
#include <hip/hip_runtime.h>
#include <math.h>

typedef __attribute__((ext_vector_type(8))) __bf16 bf16x8;
typedef __attribute__((ext_vector_type(4))) float f32x4;

// Problem constants (fixed by the reference)
constexpr int B = 8192;
constexpr int D = 128;
constexpr int K = 256;
constexpr int MB = B / 16;   // 512 main blocks, 16 rows each

// ws layout (floats)
//   part_reg  : [0, 256)
//   cc        : [256, 512)
//   part_loss : [512, 1024)
//   c_bf16    : [1024, 1024+16384)   (64 KB as bf16[256][128])

// --- Kernel 1: prep — reg term (blocks 0..K) + c->bf16 + cc (blocks K..K+15)
__global__ __launch_bounds__(256) void prep_kernel(const float* __restrict__ centers,
                                                   float* __restrict__ part_reg,
                                                   float* __restrict__ cc,
                                                   bf16x8* __restrict__ cbu) {
  __shared__ float red[4];
  const int lane = threadIdx.x & 63;
  const int wid  = threadIdx.x >> 6;
  if (blockIdx.x < K) {
    // part_reg[i] = -log(min_{j!=i} ||c_i - c_j||^2)  (fp32 exact)
    const int i = blockIdx.x;
    const int j = threadIdx.x;
    const float* ci = centers + (size_t)i * D;
    const float* cj = centers + (size_t)j * D;
    float pd = 0.f;
#pragma unroll
    for (int q = 0; q < D / 4; ++q) {
      float4 a  = reinterpret_cast<const float4*>(ci)[q];
      float4 bq = reinterpret_cast<const float4*>(cj)[q];
      float dx = a.x - bq.x, dy = a.y - bq.y, dz = a.z - bq.z, dw = a.w - bq.w;
      pd = fmaf(dx, dx, fmaf(dy, dy, fmaf(dz, dz, fmaf(dw, dw, pd))));
    }
    if (j == i) pd = INFINITY;
#pragma unroll
    for (int off = 32; off; off >>= 1) pd = fminf(pd, __shfl_xor(pd, off));
    if (lane == 0) red[wid] = pd;
    __syncthreads();
    if (threadIdx.x == 0) {
      float m = fminf(fminf(red[0], red[1]), fminf(red[2], red[3]));
      part_reg[i] = -logf(m);
    }
  } else {
    // centers -> bf16 (row-major [256][128]) + cc[k] = ||c_k||^2 in fp32
    const int ci = blockIdx.x - K;            // 0..15, 16 rows each
    const int t = threadIdx.x;
    const int base = ci * 2048 + t * 8;       // fp32 element index
    const float4* p = reinterpret_cast<const float4*>(centers + base);
    float4 f0 = p[0], f1 = p[1];
    bf16x8 o;
    o[0] = (__bf16)f0.x; o[1] = (__bf16)f0.y; o[2] = (__bf16)f0.z; o[3] = (__bf16)f0.w;
    o[4] = (__bf16)f1.x; o[5] = (__bf16)f1.y; o[6] = (__bf16)f1.z; o[7] = (__bf16)f1.w;
    cbu[ci * 256 + t] = o;
    float sq = f0.x * f0.x + f0.y * f0.y + f0.z * f0.z + f0.w * f0.w +
               f1.x * f1.x + f1.y * f1.y + f1.z * f1.z + f1.w * f1.w;
#pragma unroll
    for (int off = 1; off < 16; off <<= 1) sq += __shfl_xor(sq, off);
    if ((t & 15) == 0) cc[base / 128] = sq;
  }
}

// --- Kernel 2: main — MFMA bf16, block = 16 rows x 256 cols, 4 waves -------
// Wave w owns cols [w*64, w*64+64). A-frag: h rows (fp32->bf16 in-kernel,
// hh as fp32 byproduct). B-frag: c_bf16 rows (B^T pattern). C-map (m89):
// col = lane&15, row = (lane>>4)*4 + reg.
__global__ __launch_bounds__(256) void main_kernel(
    const float* __restrict__ h, const int* __restrict__ y,
    const bf16x8* __restrict__ cbu, const float* __restrict__ cc,
    float* __restrict__ part_loss) {
  const int t = threadIdx.x;
  const int w = t >> 6;
  const int l = t & 63;
  const int lr = l & 15;   // A row / C col (in-tile)
  const int lg = l >> 4;   // k-group / C row-group
  const int r0 = blockIdx.x * 16;
  const int n0 = w * 64;

  // ---- A fragments (4 k-chunks) + hh from the same fp32 values ----
  const float* hrow = h + (size_t)(r0 + lr) * D + lg * 8;
  bf16x8 a[4];
  float sq = 0.f;
#pragma unroll
  for (int c = 0; c < 4; ++c) {
    const float4* hp = reinterpret_cast<const float4*>(hrow + c * 32);
    float4 f0 = hp[0], f1 = hp[1];
    sq = fmaf(f0.x, f0.x, fmaf(f0.y, f0.y, fmaf(f0.z, f0.z, fmaf(f0.w, f0.w, sq))));
    sq = fmaf(f1.x, f1.x, fmaf(f1.y, f1.y, fmaf(f1.z, f1.z, fmaf(f1.w, f1.w, sq))));
    a[c][0] = (__bf16)f0.x; a[c][1] = (__bf16)f0.y;
    a[c][2] = (__bf16)f0.z; a[c][3] = (__bf16)f0.w;
    a[c][4] = (__bf16)f1.x; a[c][5] = (__bf16)f1.y;
    a[c][6] = (__bf16)f1.z; a[c][7] = (__bf16)f1.w;
  }
  // lanes {lr, lr+16, lr+32, lr+48} hold k-partials of row r0+lr -> combine
  sq += __shfl_xor(sq, 16);
  sq += __shfl_xor(sq, 32);
  // redistribute: this lane needs hh of rows r0 + lg*4 + j (held at lane lg*4+j)
  float hh_r[4];
  int y_r[4];
#pragma unroll
  for (int j = 0; j < 4; ++j) {
    hh_r[j] = __int_as_float(
        __builtin_amdgcn_ds_bpermute((lg * 4 + j) << 2, __float_as_int(sq)));
    y_r[j] = y[r0 + lg * 4 + j];
  }

  // ---- MFMA: 4 col-tiles x 4 k-chunks ----
  f32x4 zero = {0.f, 0.f, 0.f, 0.f};
  f32x4 acc[4] = {zero, zero, zero, zero};
#pragma unroll
  for (int c = 0; c < 4; ++c) {
    bf16x8 bb[4];
#pragma unroll
    for (int n = 0; n < 4; ++n)
      bb[n] = cbu[(size_t)(n0 + n * 16 + lr) * (D / 8) + c * 4 + lg];
#pragma unroll
    for (int n = 0; n < 4; ++n)
      asm("v_mfma_f32_16x16x32_bf16 %0, %1, %2, %0"
          : "+v"(acc[n])
          : "v"(a[c]), "v"(bb[n]));
  }

  // ---- epilogue: dist, exp, y-gather, row reductions ----
  float s[4] = {0.f, 0.f, 0.f, 0.f};
  float dyv[4] = {0.f, 0.f, 0.f, 0.f};
#pragma unroll
  for (int n = 0; n < 4; ++n) {
    const int colg = n0 + n * 16 + lr;
    const float ccv = cc[colg];
#pragma unroll
    for (int j = 0; j < 4; ++j) {
      float dist = fmaxf(fmaf(-2.f, acc[n][j], hh_r[j] + ccv), 0.f);
      if (y_r[j] == colg) dyv[j] = dist;
      s[j] += __expf(-sqrtf(dist));
    }
  }
  // reduce across the 16 lanes covering each row's cols
#pragma unroll
  for (int j = 0; j < 4; ++j) {
#pragma unroll
    for (int off = 1; off < 16; off <<= 1) {
      s[j] += __shfl_xor(s[j], off);
      dyv[j] += __shfl_xor(dyv[j], off);
    }
  }
  __shared__ float ls[4][16];
  __shared__ float ldy[4][16];
  if (lr == 0) {
#pragma unroll
    for (int j = 0; j < 4; ++j) {
      ls[w][lg * 4 + j] = s[j];
      ldy[w][lg * 4 + j] = dyv[j];
    }
  }
  __syncthreads();
  if (t < 16) {
    float stot = (ls[0][t] + ls[1][t]) + (ls[2][t] + ls[3][t]);
    float dtot = (ldy[0][t] + ldy[1][t]) + (ldy[2][t] + ldy[3][t]);
    float v = dtot + logf(stot);
#pragma unroll
    for (int off = 1; off < 16; off <<= 1) v += __shfl_xor(v, off);
    if (t == 0) part_loss[blockIdx.x] = v;
  }
}

// --- Kernel 3: final deterministic reduction -------------------------------
__global__ __launch_bounds__(256) void final_kernel(
    const float* __restrict__ part_loss, const float* __restrict__ part_reg,
    float* __restrict__ out) {
  const int t = threadIdx.x;
  float v = part_reg[t] + (part_loss[t] + part_loss[t + 256]) * (1.0f / (float)B);
  const int lane = t & 63;
  const int wid  = t >> 6;
#pragma unroll
  for (int off = 32; off; off >>= 1) v += __shfl_xor(v, off);
  __shared__ float red[4];
  if (lane == 0) red[wid] = v;
  __syncthreads();
  if (t == 0) out[0] = red[0] + red[1] + red[2] + red[3];
}

extern "C" void kernel_launch(void* const* d_in, const int* in_sizes, int n_in,
                              void* d_out, int out_size, void* d_ws, size_t ws_size,
                              hipStream_t stream) {
  const float* h       = (const float*)d_in[0];
  const int*   y       = (const int*)d_in[1];
  const float* centers = (const float*)d_in[2];
  float* out = (float*)d_out;
  float* ws  = (float*)d_ws;

  float*  part_reg  = ws;
  float*  cc        = ws + 256;
  float*  part_loss = ws + 512;
  bf16x8* cbu       = reinterpret_cast<bf16x8*>(ws + 1024);

  prep_kernel<<<K + 16, 256, 0, stream>>>(centers, part_reg, cc, cbu);
  main_kernel<<<MB, 256, 0, stream>>>(h, y, cbu, cc, part_loss);
  final_kernel<<<1, 256, 0, stream>>>(part_loss, part_reg, out);
}